// Round 5
// baseline (3675.420 us; speedup 1.0000x reference)
//
#include <hip/hip_runtime.h>
#include <hip/hip_bf16.h>
#include <cstddef>

// Problem constants
constexpr int B = 128;
constexpr int T = 500;
constexpr int C = 128;     // n_maps
constexpr int CIN = 80;    // n_mels
constexpr int NL = 35;     // labels
constexpr size_t NBCT = (size_t)B * C * T;  // 8,192,000 floats
constexpr int WPAD = 132;                   // LDS i-stride (conflict-free, measured)
constexpr int I0 = 96;                      // conv0 padded input channels
constexpr int IPAD0 = 104;                  // conv0 LDS i-stride
constexpr int NT0 = 64;                     // conv0 t-tile
constexpr int NTC = 128;                    // main conv t-tile
constexpr int ROWSC = NTC + 8;              // 136 staged rows (KW=9 halo)
constexpr int NSLOT = 49;                   // stats slots: 16*(t1,t3,t2) + conv0

// Dynamic LDS layout for main convs
constexpr int WSLICE_H = 16 * C * 8;            // one kw-slice = 16384 halves = 32KB
constexpr int SMEM_W_BYTES = 2 * WSLICE_H * 2;  // double-buffered = 65536 B
constexpr int SMEM_IN_BYTES = ROWSC * WPAD * 2; // 35904 B
constexpr int SMEM_F_OFF = SMEM_W_BYTES + SMEM_IN_BYTES;
constexpr int SMEM_BYTES = SMEM_F_OFF + 4 * C * 4;  // +2048 = 103488 B

typedef __attribute__((ext_vector_type(8))) _Float16 half8;  // 8 fp16 = 4 VGPR
typedef __attribute__((ext_vector_type(4))) _Float16 half4;
typedef __attribute__((ext_vector_type(4))) float f32x4;

// Static device scratch. Activations in [b][t][c] layout.
__device__ float g_z[NBCT];          // RK4 state (fp32)
__device__ float g_acc[NBCT];        // RK4 k-accumulator (fp32)
__device__ _Float16 g_zi16[NBCT];    // conv input snapshot (fp16)
__device__ _Float16 g_t1[NBCT];      // conv1 out (fp16, pre-BN)
__device__ _Float16 g_t2[NBCT];      // conv2 out (fp16, pre-BN)
__device__ _Float16 g_t3[NBCT];      // conv3 out (fp16, pre-BN)
__device__ float g_S[NSLOT * C], g_Q[NSLOT * C];  // global stat accumulators
__device__ float g_featp[B * 4 * C];              // head partial sums
// conv0 weights, layout [kw][o][i] (i-stride I0), fp16
__device__ _Float16 g_w0f[3 * C * I0];
// main conv weights, MFMA-native layout [kw][kseg=i>>3][o][j=i&7], fp16
// => each kw-slice is a contiguous 32KB block (global_load_lds-ready)
__device__ _Float16 g_w1f[9 * C * C];
__device__ _Float16 g_w2f[9 * C * C];
__device__ _Float16 g_w3f[1 * C * C];

__device__ inline half8 h8zero() {
  half8 v;
#pragma unroll
  for (int j = 0; j < 8; j++) v[j] = (_Float16)0.f;
  return v;
}

// Async global->LDS, 16B per lane. LDS dest = wave-uniform base + lane*16.
__device__ inline void gload_lds16(const void* g, void* l) {
  __builtin_amdgcn_global_load_lds(
      (const __attribute__((address_space(1))) unsigned int*)g,
      (__attribute__((address_space(3))) unsigned int*)l, 16, 0, 0);
}

// ---------------------------------------------------------------------------
// Zero the stat accumulators (once per launch, up front).
// ---------------------------------------------------------------------------
__global__ __launch_bounds__(256) void zero_stats(float* __restrict__ S,
                                                  float* __restrict__ Q) {
  int i = blockIdx.x * 256 + threadIdx.x;
  if (i < NSLOT * C) {
    S[i] = 0.f;
    Q[i] = 0.f;
  }
}

// ---------------------------------------------------------------------------
// Weight prep: w [O][I][KW] fp32 -> fp16, layout [kw][i>>3][o][i&7]
// ---------------------------------------------------------------------------
template <int KW>
__global__ __launch_bounds__(256) void prep_weights_f16(
    const float* __restrict__ w, _Float16* __restrict__ wf) {
  int idx = blockIdx.x * 256 + threadIdx.x;
  if (idx >= C * C * KW) return;
  int kw = idx % KW;
  int i = (idx / KW) % C;
  int o = idx / (KW * C);
  size_t dst = (((size_t)kw * 16 + (i >> 3)) * C + o) * 8 + (i & 7);
  wf[dst] = (_Float16)w[idx];
}

// conv0 weights: w0 [O=128][I=80][3] -> [3][O][I0=96] fp16 (zero-padded i>=80)
__global__ __launch_bounds__(256) void prep_w0_f16(
    const float* __restrict__ w, _Float16* __restrict__ wf) {
  int idx = blockIdx.x * 256 + threadIdx.x;
  if (idx >= 3 * C * I0) return;
  int i = idx % I0;
  int o = (idx / I0) % C;
  int kw = idx / (I0 * C);
  float v = 0.f;
  if (i < CIN) v = w[((size_t)o * CIN + i) * 3 + kw];
  wf[((size_t)kw * C + o) * I0 + i] = (_Float16)v;
}

// ---------------------------------------------------------------------------
// Epilogues: store D tiles (fp32 or fp16 out) + per-channel partial stats.
// D layout (16x16x32): col(t)=lane&15, row(o)=quad*4+reg.
// ---------------------------------------------------------------------------
template <int NG, int NTG>
__device__ inline void store_and_stats_f(f32x4 (&dacc)[NG][NTG],
                                         float* __restrict__ outb,
                                         float* __restrict__ ssum,
                                         float* __restrict__ ssq, int tbase,
                                         int og0, int quad, int m15) {
#pragma unroll
  for (int g = 0; g < NG; g++) {
    float rs[4] = {0.f, 0.f, 0.f, 0.f}, rq[4] = {0.f, 0.f, 0.f, 0.f};
#pragma unroll
    for (int tg = 0; tg < NTG; tg++) {
      int t = tbase + tg * 16 + m15;
      bool valid = t < T;
      f32x4 d = dacc[g][tg];
      if (valid)
        *(f32x4*)(outb + (size_t)t * C + (og0 + g) * 16 + quad * 4) = d;
#pragma unroll
      for (int r = 0; r < 4; r++) {
        float v = valid ? d[r] : 0.f;
        rs[r] += v;
        rq[r] += v * v;
      }
    }
#pragma unroll
    for (int sh = 1; sh < 16; sh <<= 1) {
#pragma unroll
      for (int r = 0; r < 4; r++) {
        rs[r] += __shfl_xor(rs[r], sh);
        rq[r] += __shfl_xor(rq[r], sh);
      }
    }
    if (m15 == 0) {
      int o = (og0 + g) * 16 + quad * 4;
#pragma unroll
      for (int r = 0; r < 4; r++) {
        atomicAdd(&ssum[o + r], rs[r]);
        atomicAdd(&ssq[o + r], rq[r]);
      }
    }
  }
}

template <int NG, int NTG>
__device__ inline void store_and_stats_h(f32x4 (&dacc)[NG][NTG],
                                         _Float16* __restrict__ outb,
                                         float* __restrict__ ssum,
                                         float* __restrict__ ssq, int tbase,
                                         int og0, int quad, int m15) {
#pragma unroll
  for (int g = 0; g < NG; g++) {
    float rs[4] = {0.f, 0.f, 0.f, 0.f}, rq[4] = {0.f, 0.f, 0.f, 0.f};
#pragma unroll
    for (int tg = 0; tg < NTG; tg++) {
      int t = tbase + tg * 16 + m15;
      bool valid = t < T;
      f32x4 d = dacc[g][tg];
      if (valid) {
        half4 h;
#pragma unroll
        for (int r = 0; r < 4; r++) h[r] = (_Float16)d[r];
        *(half4*)(outb + (size_t)t * C + (og0 + g) * 16 + quad * 4) = h;
      }
#pragma unroll
      for (int r = 0; r < 4; r++) {
        float v = valid ? d[r] : 0.f;
        rs[r] += v;
        rq[r] += v * v;
      }
    }
#pragma unroll
    for (int sh = 1; sh < 16; sh <<= 1) {
#pragma unroll
      for (int r = 0; r < 4; r++) {
        rs[r] += __shfl_xor(rs[r], sh);
        rq[r] += __shfl_xor(rq[r], sh);
      }
    }
    if (m15 == 0) {
      int o = (og0 + g) * 16 + quad * 4;
#pragma unroll
      for (int r = 0; r < 4; r++) {
        atomicAdd(&ssum[o + r], rs[r]);
        atomicAdd(&ssq[o + r], rq[r]);
      }
    }
  }
}

// ---------------------------------------------------------------------------
// Fused conv1 (KW=9, PAD=4) + conv3 (KW=1), kw-sliced LDS weight staging:
// 10 slices (9x w1-kw + 1x w3), each 32KB, double-buffered in LDS via async
// global_load_lds (weights layout is already linear per slice). The round
// loop has ZERO global loads — A from LDS (conflict-free 16-lane runs),
// B from the input tile. NT=128, 512thr/8 waves: og0=(wv&3)*2, t-half=wv>>2
// (NG=2 x NTG=4). 1 block/CU (103.5KB LDS); round loop is LDS-BW/MFMA bound.
// ---------------------------------------------------------------------------
__global__ __launch_bounds__(512) void conv13(
    const _Float16* __restrict__ in, const _Float16* __restrict__ w9,
    const _Float16* __restrict__ w1, _Float16* __restrict__ out1,
    _Float16* __restrict__ out3, float* __restrict__ gS1,
    float* __restrict__ gQ1, float* __restrict__ gS3,
    float* __restrict__ gQ3) {
  constexpr int PAD = 4;
  extern __shared__ char smem[];
  _Float16* shW = (_Float16*)smem;
  _Float16* shin = (_Float16*)(smem + SMEM_W_BYTES);
  float* ssum1 = (float*)(smem + SMEM_F_OFF);
  float* ssq1 = ssum1 + C;
  float* ssum3 = ssum1 + 2 * C;
  float* ssq3 = ssum1 + 3 * C;

  const int tid = threadIdx.x;
  const int t0 = blockIdx.x * NTC;
  const int b = blockIdx.y;

  const int wv = tid >> 6;
  const int lane = tid & 63;
  const int quad = lane >> 4;
  const int m15 = lane & 15;
  const int og0 = (wv & 3) * 2;
  const int tr0 = (wv >> 2) * 64;

  // Issue one 32KB weight slice into LDS buffer buf (8 waves x 4KB each).
  auto issueW = [&](const _Float16* src, int buf) {
    const char* g = (const char*)src;
    char* l = (char*)(shW + buf * WSLICE_H);
    const int base = wv * 4096;
#pragma unroll
    for (int j = 0; j < 4; ++j) {
      int off = base + j * 1024;
      gload_lds16(g + off + lane * 16, l + off);
    }
  };

  issueW(w9, 0);  // prefetch slice 0 ASAP

  if (tid < 128) {
    ssum1[tid] = 0.f; ssq1[tid] = 0.f;
    ssum3[tid] = 0.f; ssq3[tid] = 0.f;
  }

  // Stage fp16 input rows [t0-PAD, t0-PAD+ROWSC) — pure copy, 16B loads.
  const _Float16* __restrict__ inb = in + (size_t)b * T * C;
  for (int e = tid; e < ROWSC * 16; e += 512) {
    int r = e >> 4;
    int c8 = e & 15;
    int t = t0 - PAD + r;
    half8 v = h8zero();
    if (t >= 0 && t < T) v = *(const half8*)(inb + (size_t)t * C + c8 * 8);
    *(half8*)&shin[r * WPAD + c8 * 8] = v;
  }

  f32x4 d1[2][4], d3[2][4];
#pragma unroll
  for (int g = 0; g < 2; g++)
#pragma unroll
    for (int tg = 0; tg < 4; tg++) {
      d1[g][tg] = f32x4{0.f, 0.f, 0.f, 0.f};
      d3[g][tg] = f32x4{0.f, 0.f, 0.f, 0.f};
    }

  auto computeSlice = [&](int buf, int rofs, f32x4 (&D)[2][4]) {
    const _Float16* __restrict__ Wb = shW + buf * WSLICE_H;
#pragma unroll
    for (int ic = 0; ic < 4; ++ic) {
      const int kseg = ic * 4 + quad;
      half8 af[2];
#pragma unroll
      for (int g = 0; g < 2; g++)
        af[g] = *(const half8*)(Wb + (kseg * C + (og0 + g) * 16 + m15) * 8);
      const int kof = ic * 32 + quad * 8;
      half8 bf[4];
#pragma unroll
      for (int tg = 0; tg < 4; tg++)
        bf[tg] = *(const half8*)(shin + (tr0 + tg * 16 + m15 + rofs) * WPAD + kof);
#pragma unroll
      for (int g = 0; g < 2; g++)
#pragma unroll
        for (int tg = 0; tg < 4; tg++)
          D[g][tg] = __builtin_amdgcn_mfma_f32_16x16x32_f16(af[g], bf[tg],
                                                            D[g][tg], 0, 0, 0);
    }
  };

  // Slice loop: barrier drains vmcnt (slice landed) + lgkm (staging done),
  // then prefetch next slice into the other buffer, then compute this one.
  int buf = 0;
  for (int sl = 0; sl < 10; ++sl) {
    __syncthreads();
    if (sl + 1 < 10)
      issueW((sl + 1 < 9) ? (w9 + (size_t)(sl + 1) * WSLICE_H) : w1, buf ^ 1);
    if (sl < 9)
      computeSlice(buf, sl, d1);
    else
      computeSlice(buf, PAD, d3);
    buf ^= 1;
  }

  _Float16* __restrict__ o1b = out1 + (size_t)b * T * C;
  _Float16* __restrict__ o3b = out3 + (size_t)b * T * C;
  store_and_stats_h<2, 4>(d1, o1b, ssum1, ssq1, t0 + tr0, og0, quad, m15);
  store_and_stats_h<2, 4>(d3, o3b, ssum3, ssq3, t0 + tr0, og0, quad, m15);
  __syncthreads();
  if (tid < 128) {
    atomicAdd(&gS1[tid], ssum1[tid]);
    atomicAdd(&gQ1[tid], ssq1[tid]);
    atomicAdd(&gS3[tid], ssum3[tid]);
    atomicAdd(&gQ3[tid], ssq3[tid]);
  }
}

// ---------------------------------------------------------------------------
// conv2 (KW=9, PAD=4): same kw-sliced LDS weight staging; BN+relu applied
// during input staging from inline stats (producer finished, stream order).
// ---------------------------------------------------------------------------
__global__ __launch_bounds__(512) void conv2_bn(
    const _Float16* __restrict__ in, const _Float16* __restrict__ wf,
    const float* __restrict__ bnS, const float* __restrict__ bnQ,
    _Float16* __restrict__ out, float* __restrict__ gS,
    float* __restrict__ gQ) {
  constexpr int PAD = 4;
  extern __shared__ char smem[];
  _Float16* shW = (_Float16*)smem;
  _Float16* shin = (_Float16*)(smem + SMEM_W_BYTES);
  float* ssum = (float*)(smem + SMEM_F_OFF);
  float* ssq = ssum + C;
  float* sbm = ssum + 2 * C;
  float* sbr = ssum + 3 * C;

  const int tid = threadIdx.x;
  const int t0 = blockIdx.x * NTC;
  const int b = blockIdx.y;

  const int wv = tid >> 6;
  const int lane = tid & 63;
  const int quad = lane >> 4;
  const int m15 = lane & 15;
  const int og0 = (wv & 3) * 2;
  const int tr0 = (wv >> 2) * 64;

  auto issueW = [&](const _Float16* src, int buf) {
    const char* g = (const char*)src;
    char* l = (char*)(shW + buf * WSLICE_H);
    const int base = wv * 4096;
#pragma unroll
    for (int j = 0; j < 4; ++j) {
      int off = base + j * 1024;
      gload_lds16(g + off + lane * 16, l + off);
    }
  };

  issueW(wf, 0);

  if (tid < 128) {
    const float invn = 1.f / 64000.f;
    float m = bnS[tid] * invn;
    sbm[tid] = m;
    sbr[tid] = rsqrtf(bnQ[tid] * invn - m * m + 1e-5f);
    ssum[tid] = 0.f;
    ssq[tid] = 0.f;
  }
  __syncthreads();  // BN params ready before staging uses them

  const _Float16* __restrict__ inb = in + (size_t)b * T * C;
  for (int e = tid; e < ROWSC * 16; e += 512) {
    int r = e >> 4;
    int c8 = e & 15;
    int t = t0 - PAD + r;
    half8 v = h8zero();
    if (t >= 0 && t < T) {
      half8 u = *(const half8*)(inb + (size_t)t * C + c8 * 8);
      int c = c8 * 8;
#pragma unroll
      for (int j = 0; j < 8; j++) {
        float f = (float)u[j];
        f = fmaxf((f - sbm[c + j]) * sbr[c + j], 0.f);
        v[j] = (_Float16)f;
      }
    }
    *(half8*)&shin[r * WPAD + c8 * 8] = v;
  }

  f32x4 dacc[2][4];
#pragma unroll
  for (int g = 0; g < 2; g++)
#pragma unroll
    for (int tg = 0; tg < 4; tg++) dacc[g][tg] = f32x4{0.f, 0.f, 0.f, 0.f};

  int buf = 0;
  for (int sl = 0; sl < 9; ++sl) {
    __syncthreads();
    if (sl + 1 < 9) issueW(wf + (size_t)(sl + 1) * WSLICE_H, buf ^ 1);
    const _Float16* __restrict__ Wb = shW + buf * WSLICE_H;
#pragma unroll
    for (int ic = 0; ic < 4; ++ic) {
      const int kseg = ic * 4 + quad;
      half8 af[2];
#pragma unroll
      for (int g = 0; g < 2; g++)
        af[g] = *(const half8*)(Wb + (kseg * C + (og0 + g) * 16 + m15) * 8);
      const int kof = ic * 32 + quad * 8;
      half8 bf[4];
#pragma unroll
      for (int tg = 0; tg < 4; tg++)
        bf[tg] = *(const half8*)(shin + (tr0 + tg * 16 + m15 + sl) * WPAD + kof);
#pragma unroll
      for (int g = 0; g < 2; g++)
#pragma unroll
        for (int tg = 0; tg < 4; tg++)
          dacc[g][tg] = __builtin_amdgcn_mfma_f32_16x16x32_f16(
              af[g], bf[tg], dacc[g][tg], 0, 0, 0);
    }
    buf ^= 1;
  }

  _Float16* __restrict__ outb = out + (size_t)b * T * C;
  store_and_stats_h<2, 4>(dacc, outb, ssum, ssq, t0 + tr0, og0, quad, m15);
  __syncthreads();
  if (tid < 128) {
    atomicAdd(&gS[tid], ssum[tid]);
    atomicAdd(&gQ[tid], ssq[tid]);
  }
}

// ---------------------------------------------------------------------------
// conv0: single fp16 16x16x32 MFMA. in x[B][80][T] (t fastest), K=96(pad) x 3.
// Output z fp32 (state). 256 threads, one dispatch — unchanged.
// ---------------------------------------------------------------------------
__global__ __launch_bounds__(256) void conv0_mfma(
    const float* __restrict__ in, const _Float16* __restrict__ wf,
    float* __restrict__ out, float* __restrict__ gS, float* __restrict__ gQ) {
  constexpr int KW = 3, PAD = 1;
  constexpr int ROWS = NT0 + KW - 1;  // 66
  __shared__ __align__(16) _Float16 sh[ROWS * IPAD0];
  __shared__ float ssum[C], ssq[C];

  const int tid = threadIdx.x;
  const int tile = blockIdx.x;
  const int b = blockIdx.y;
  const int t0 = tile * NT0;

  if (tid < 128) { ssum[tid] = 0.f; ssq[tid] = 0.f; }
  __syncthreads();

  const float* __restrict__ inb = in + (size_t)b * CIN * T;
  for (int e = tid; e < I0 * ROWS; e += 256) {
    int i = e / ROWS;
    int r = e % ROWS;
    int t = t0 - PAD + r;
    float v = 0.f;
    if (i < CIN && t >= 0 && t < T) v = inb[(size_t)i * T + t];
    sh[r * IPAD0 + i] = (_Float16)v;
  }
  __syncthreads();

  const int wv = tid >> 6;
  const int lane = tid & 63;
  const int quad = lane >> 4;
  const int m15 = lane & 15;
  const int og0 = wv * 2;

  f32x4 dacc[2][4];
#pragma unroll
  for (int g = 0; g < 2; g++)
#pragma unroll
    for (int tg = 0; tg < 4; tg++) dacc[g][tg] = f32x4{0.f, 0.f, 0.f, 0.f};

  for (int kw = 0; kw < KW; kw++) {
    const _Float16* __restrict__ wk = wf + (size_t)kw * C * I0;
#pragma unroll
    for (int ic = 0; ic < 3; ic++) {
      const int kof = ic * 32 + quad * 8;
      half8 af[2];
#pragma unroll
      for (int g = 0; g < 2; g++) {
        size_t off = (size_t)((og0 + g) * 16 + m15) * I0 + kof;
        af[g] = *(const half8*)(wk + off);
      }
      half8 bf[4];
#pragma unroll
      for (int tg = 0; tg < 4; tg++) {
        int off = (tg * 16 + m15 + kw) * IPAD0 + kof;
        bf[tg] = *(const half8*)(sh + off);
      }
#pragma unroll
      for (int g = 0; g < 2; g++)
#pragma unroll
        for (int tg = 0; tg < 4; tg++)
          dacc[g][tg] = __builtin_amdgcn_mfma_f32_16x16x32_f16(
              af[g], bf[tg], dacc[g][tg], 0, 0, 0);
    }
  }

  float* __restrict__ outb = out + (size_t)b * T * C;
  store_and_stats_f<2, 4>(dacc, outb, ssum, ssq, t0, og0, quad, m15);
  __syncthreads();
  if (tid < 128) {
    atomicAdd(&gS[tid], ssum[tid]);
    atomicAdd(&gQ[tid], ssq[tid]);
  }
}

// ---------------------------------------------------------------------------
// z = relu((z - m[c]) * r[c]) in place (fp32) + fp16 snapshot for conv13.
// ---------------------------------------------------------------------------
__global__ __launch_bounds__(256) void apply_bn_relu(
    float* __restrict__ x, const float* __restrict__ S,
    const float* __restrict__ Q, _Float16* __restrict__ zh) {
  __shared__ float sm[C], sr[C];
  if (threadIdx.x < 128) {
    const float invn = 1.f / 64000.f;
    float m = S[threadIdx.x] * invn;
    sm[threadIdx.x] = m;
    sr[threadIdx.x] = rsqrtf(Q[threadIdx.x] * invn - m * m + 1e-5f);
  }
  __syncthreads();
  const size_t total4 = NBCT / 4;
  size_t stride = (size_t)gridDim.x * 256;
  for (size_t i4 = (size_t)blockIdx.x * 256 + threadIdx.x; i4 < total4;
       i4 += stride) {
    int c = (int)((i4 & 31) * 4);
    float4 v = ((float4*)x)[i4];
    v.x = fmaxf((v.x - sm[c]) * sr[c], 0.f);
    v.y = fmaxf((v.y - sm[c + 1]) * sr[c + 1], 0.f);
    v.z = fmaxf((v.z - sm[c + 2]) * sr[c + 2], 0.f);
    v.w = fmaxf((v.w - sm[c + 3]) * sr[c + 3], 0.f);
    ((float4*)x)[i4] = v;
    half4 h;
    h[0] = (_Float16)v.x;
    h[1] = (_Float16)v.y;
    h[2] = (_Float16)v.z;
    h[3] = (_Float16)v.w;
    *(half4*)(zh + i4 * 4) = h;
  }
}

// ---------------------------------------------------------------------------
// combine: k = relu(bn2(t2) + relu(bn3(t3))); RK4 update.
// t2/t3 fp16; z/acc fp32; zi16 (fp16 next-conv input) always written;
// z (fp32 state) written only on fin.
// ---------------------------------------------------------------------------
__global__ __launch_bounds__(256) void combine_kernel(
    const _Float16* __restrict__ t2, const _Float16* __restrict__ t3,
    const float* __restrict__ S2, const float* __restrict__ Q2,
    const float* __restrict__ S3, const float* __restrict__ Q3,
    float* __restrict__ z, float* __restrict__ acc,
    _Float16* __restrict__ zi16, float wacc, float anext, int init, int fin) {
  __shared__ float sm2[C], sr2[C], sm3[C], sr3[C];
  if (threadIdx.x < 128) {
    const float invn = 1.f / 64000.f;
    float m2v = S2[threadIdx.x] * invn;
    sm2[threadIdx.x] = m2v;
    sr2[threadIdx.x] = rsqrtf(Q2[threadIdx.x] * invn - m2v * m2v + 1e-5f);
    float m3v = S3[threadIdx.x] * invn;
    sm3[threadIdx.x] = m3v;
    sr3[threadIdx.x] = rsqrtf(Q3[threadIdx.x] * invn - m3v * m3v + 1e-5f);
  }
  __syncthreads();
  const size_t total4 = NBCT / 4;
  size_t stride = (size_t)gridDim.x * 256;
  for (size_t i4 = (size_t)blockIdx.x * 256 + threadIdx.x; i4 < total4;
       i4 += stride) {
    int c = (int)((i4 & 31) * 4);
    size_t off = i4 * 4;
    half4 h2 = *(const half4*)(t2 + off);
    half4 h3 = *(const half4*)(t3 + off);
    float4 vz = *(const float4*)(z + off);
    float k[4];
#pragma unroll
    for (int j = 0; j < 4; j++) {
      float f2 = (float)h2[j];
      float f3 = (float)h3[j];
      k[j] = fmaxf((f2 - sm2[c + j]) * sr2[c + j] +
                       fmaxf((f3 - sm3[c + j]) * sr3[c + j], 0.f),
                   0.f);
    }
    float va[4];
    if (init) {
#pragma unroll
      for (int j = 0; j < 4; j++) va[j] = wacc * k[j];
    } else {
      float4 a = *(const float4*)(acc + off);
      va[0] = a.x + wacc * k[0];
      va[1] = a.y + wacc * k[1];
      va[2] = a.z + wacc * k[2];
      va[3] = a.w + wacc * k[3];
    }
    float vzf[4] = {vz.x, vz.y, vz.z, vz.w};
    float vo[4];
    if (fin) {
#pragma unroll
      for (int j = 0; j < 4; j++) vo[j] = vzf[j] + anext * va[j];
      float4 w4 = make_float4(vo[0], vo[1], vo[2], vo[3]);
      *(float4*)(z + off) = w4;
    } else {
      float4 a4 = make_float4(va[0], va[1], va[2], va[3]);
      *(float4*)(acc + off) = a4;
#pragma unroll
      for (int j = 0; j < 4; j++) vo[j] = vzf[j] + anext * k[j];
    }
    half4 ho;
#pragma unroll
    for (int j = 0; j < 4; j++) ho[j] = (_Float16)vo[j];
    *(half4*)(zi16 + off) = ho;
  }
}

// ---------------------------------------------------------------------------
// head, phase 1: partial t-sums. grid (B, 4), each block sums 125 t's.
// ---------------------------------------------------------------------------
__global__ __launch_bounds__(256) void feat_part(
    const float* __restrict__ z, float* __restrict__ fp) {
  const int b = blockIdx.x;
  const int s = blockIdx.y;
  const int c = threadIdx.x & 127;
  const int h = threadIdx.x >> 7;
  const float* zb = z + (size_t)b * T * C;
  float sum = 0.f;
  for (int t = s * 125 + h; t < (s + 1) * 125; t += 2)
    sum += zb[(size_t)t * C + c];
  __shared__ float sf[2][C];
  sf[h][c] = sum;
  __syncthreads();
  if (threadIdx.x < 128)
    fp[((size_t)b * 4 + s) * C + threadIdx.x] =
        sf[0][threadIdx.x] + sf[1][threadIdx.x];
}

// head, phase 2: feat = sum(partials)/500; out = feat @ ow^T + ob.
__global__ __launch_bounds__(256) void head2(
    const float* __restrict__ fp, const float* __restrict__ ow,
    const float* __restrict__ ob, float* __restrict__ out) {
  const int b = blockIdx.x;
  __shared__ float feat[C];
  if (threadIdx.x < 128) {
    float s = 0.f;
#pragma unroll
    for (int p = 0; p < 4; p++) s += fp[((size_t)b * 4 + p) * C + threadIdx.x];
    feat[threadIdx.x] = s * (1.f / 500.f);
  }
  __syncthreads();
  if (threadIdx.x < NL) {
    int l = threadIdx.x;
    float o = ob[l];
    for (int j = 0; j < C; j++) o = fmaf(feat[j], ow[l * C + j], o);
    out[b * NL + l] = o;
  }
}

// ---------------------------------------------------------------------------
extern "C" void kernel_launch(void* const* d_in, const int* in_sizes, int n_in,
                              void* d_out, int out_size, void* d_ws,
                              size_t ws_size, hipStream_t stream) {
  const float* x  = (const float*)d_in[0];
  const float* w0 = (const float*)d_in[1];
  const float* w1 = (const float*)d_in[2];
  const float* w2 = (const float*)d_in[3];
  const float* w3 = (const float*)d_in[4];
  const float* ow = (const float*)d_in[5];
  const float* ob = (const float*)d_in[6];
  float* out = (float*)d_out;

  static float *z, *acc, *Sg, *Qg, *featp;
  static _Float16 *zi16, *t1, *t2, *t3;
  static _Float16 *w0f, *w1f, *w2f, *w3f;
  static bool inited = false;
  if (!inited) {
    void* p;
#define GET(sym, var) hipGetSymbolAddress(&p, HIP_SYMBOL(sym)); var = (decltype(var))p;
    GET(g_z, z) GET(g_acc, acc) GET(g_zi16, zi16)
    GET(g_t1, t1) GET(g_t2, t2) GET(g_t3, t3)
    GET(g_S, Sg) GET(g_Q, Qg) GET(g_featp, featp)
    GET(g_w0f, w0f) GET(g_w1f, w1f) GET(g_w2f, w2f) GET(g_w3f, w3f)
#undef GET
    hipFuncSetAttribute((const void*)conv13,
                        hipFuncAttributeMaxDynamicSharedMemorySize, SMEM_BYTES);
    hipFuncSetAttribute((const void*)conv2_bn,
                        hipFuncAttributeMaxDynamicSharedMemorySize, SMEM_BYTES);
    inited = true;
  }

  // Zero stat slots + weight prep (cheap, every launch)
  zero_stats<<<(NSLOT * C + 255) / 256, 256, 0, stream>>>(Sg, Qg);
  prep_w0_f16<<<(3 * C * I0 + 255) / 256, 256, 0, stream>>>(w0, w0f);
  prep_weights_f16<9><<<(C * C * 9 + 255) / 256, 256, 0, stream>>>(w1, w1f);
  prep_weights_f16<9><<<(C * C * 9 + 255) / 256, 256, 0, stream>>>(w2, w2f);
  prep_weights_f16<1><<<(C * C * 1 + 255) / 256, 256, 0, stream>>>(w3, w3f);

  const dim3 convGrid(4, B);     // NTC=128 tiles -> 512 blocks, 1 block/CU
  const dim3 conv0Grid(8, B);    // NT0=64
  const int ewGrid = 1024;
  const float dt = 0.25f;

  // conv0 -> bn -> relu (into z fp32 + zi16 fp16). Stats slot 48.
  float* S0 = Sg + 48 * C;
  float* Q0 = Qg + 48 * C;
  conv0_mfma<<<conv0Grid, 256, 0, stream>>>(x, w0f, z, S0, Q0);
  apply_bn_relu<<<ewGrid, 256, 0, stream>>>(z, S0, Q0, zi16);

  const float waccs[4] = {1.f, 2.f, 2.f, 1.f};
  const float anexts[4] = {0.5f * dt, 0.5f * dt, dt, dt / 6.f};

  for (int step = 0; step < 4; step++) {
    for (int s = 0; s < 4; s++) {
      int base = ((step * 4 + s) * 3) * C;   // slots: t1, t3, t2
      float* S1 = Sg + base;       float* Q1 = Qg + base;
      float* S3 = Sg + base + C;   float* Q3 = Qg + base + C;
      float* S2 = Sg + base + 2*C; float* Q2 = Qg + base + 2*C;
      conv13<<<convGrid, 512, SMEM_BYTES, stream>>>(
          zi16, w1f, w3f, t1, t3, S1, Q1, S3, Q3);
      conv2_bn<<<convGrid, 512, SMEM_BYTES, stream>>>(
          t1, w2f, S1, Q1, t2, S2, Q2);
      combine_kernel<<<ewGrid, 256, 0, stream>>>(
          t2, t3, S2, Q2, S3, Q3, z, acc, zi16,
          waccs[s], anexts[s], (s == 0) ? 1 : 0, (s == 3) ? 1 : 0);
    }
  }

  feat_part<<<dim3(B, 4), 256, 0, stream>>>(z, featp);
  head2<<<B, 256, 0, stream>>>(featp, ow, ob, out);
}

// Round 6
// 2518.634 us; speedup vs baseline: 1.4593x; 1.4593x over previous
//
#include <hip/hip_runtime.h>
#include <hip/hip_bf16.h>
#include <cstddef>

// Problem constants
constexpr int B = 128;
constexpr int T = 500;
constexpr int C = 128;     // n_maps
constexpr int CIN = 80;    // n_mels
constexpr int NL = 35;     // labels
constexpr size_t NBCT = (size_t)B * C * T;  // 8,192,000 floats
constexpr int WPAD = 132;                   // LDS i-stride (conflict-free)
constexpr int I0 = 96;                      // conv0 padded input channels
constexpr int IPAD0 = 104;                  // conv0 LDS i-stride
constexpr int NT = 64;                      // conv t-tile
constexpr int NSLOT = 49;                   // stats slots: 16*(t1,t3,t2) + conv0

typedef __attribute__((ext_vector_type(8))) _Float16 half8;  // 8 fp16 = 4 VGPR
typedef __attribute__((ext_vector_type(4))) _Float16 half4;
typedef __attribute__((ext_vector_type(4))) float f32x4;

// Static device scratch. Activations in [b][t][c] layout.
__device__ float g_z[NBCT];          // RK4 state (fp32)
__device__ float g_acc[NBCT];        // RK4 k-accumulator (fp32)
__device__ _Float16 g_zi16[NBCT];    // conv input snapshot (fp16)
__device__ _Float16 g_t1[NBCT];      // conv1 out (fp16, pre-BN)
__device__ _Float16 g_t2[NBCT];      // conv2 out (fp16, pre-BN)
__device__ _Float16 g_t3[NBCT];      // conv3 out (fp16, pre-BN)
__device__ float g_S[NSLOT * C], g_Q[NSLOT * C];  // global stat accumulators
__device__ float g_featp[B * 4 * C];              // head partial sums
// conv0 weights, layout [kw][o][i] (i-stride I0), fp16
__device__ _Float16 g_w0f[3 * C * I0];
// main conv weights, MFMA-native layout [kw][kseg=i>>3][o][j=i&7], fp16
__device__ _Float16 g_w1f[9 * C * C];
__device__ _Float16 g_w2f[9 * C * C];
__device__ _Float16 g_w3f[1 * C * C];

__device__ inline half8 h8zero() {
  half8 v;
#pragma unroll
  for (int j = 0; j < 8; j++) v[j] = (_Float16)0.f;
  return v;
}

// ---------------------------------------------------------------------------
// Zero the stat accumulators (once per launch, up front).
// ---------------------------------------------------------------------------
__global__ __launch_bounds__(256) void zero_stats(float* __restrict__ S,
                                                  float* __restrict__ Q) {
  int i = blockIdx.x * 256 + threadIdx.x;
  if (i < NSLOT * C) {
    S[i] = 0.f;
    Q[i] = 0.f;
  }
}

// ---------------------------------------------------------------------------
// Weight prep: w [O][I][KW] fp32 -> fp16, layout [kw][i>>3][o][i&7]
// ---------------------------------------------------------------------------
template <int KW>
__global__ __launch_bounds__(256) void prep_weights_f16(
    const float* __restrict__ w, _Float16* __restrict__ wf) {
  int idx = blockIdx.x * 256 + threadIdx.x;
  if (idx >= C * C * KW) return;
  int kw = idx % KW;
  int i = (idx / KW) % C;
  int o = idx / (KW * C);
  size_t dst = (((size_t)kw * 16 + (i >> 3)) * C + o) * 8 + (i & 7);
  wf[dst] = (_Float16)w[idx];
}

// conv0 weights: w0 [O=128][I=80][3] -> [3][O][I0=96] fp16 (zero-padded i>=80)
__global__ __launch_bounds__(256) void prep_w0_f16(
    const float* __restrict__ w, _Float16* __restrict__ wf) {
  int idx = blockIdx.x * 256 + threadIdx.x;
  if (idx >= 3 * C * I0) return;
  int i = idx % I0;
  int o = (idx / I0) % C;
  int kw = idx / (I0 * C);
  float v = 0.f;
  if (i < CIN) v = w[((size_t)o * CIN + i) * 3 + kw];
  wf[((size_t)kw * C + o) * I0 + i] = (_Float16)v;
}

// ---------------------------------------------------------------------------
// Epilogues: store D tiles (fp32 or fp16 out) + per-channel partial stats.
// D layout (16x16x32): col(t)=lane&15, row(o)=quad*4+reg.
// ---------------------------------------------------------------------------
template <int NG, int NTG>
__device__ inline void store_and_stats_f(f32x4 (&dacc)[NG][NTG],
                                         float* __restrict__ outb,
                                         float* __restrict__ ssum,
                                         float* __restrict__ ssq, int tbase,
                                         int og0, int quad, int m15) {
#pragma unroll
  for (int g = 0; g < NG; g++) {
    float rs[4] = {0.f, 0.f, 0.f, 0.f}, rq[4] = {0.f, 0.f, 0.f, 0.f};
#pragma unroll
    for (int tg = 0; tg < NTG; tg++) {
      int t = tbase + tg * 16 + m15;
      bool valid = t < T;
      f32x4 d = dacc[g][tg];
      if (valid)
        *(f32x4*)(outb + (size_t)t * C + (og0 + g) * 16 + quad * 4) = d;
#pragma unroll
      for (int r = 0; r < 4; r++) {
        float v = valid ? d[r] : 0.f;
        rs[r] += v;
        rq[r] += v * v;
      }
    }
#pragma unroll
    for (int sh = 1; sh < 16; sh <<= 1) {
#pragma unroll
      for (int r = 0; r < 4; r++) {
        rs[r] += __shfl_xor(rs[r], sh);
        rq[r] += __shfl_xor(rq[r], sh);
      }
    }
    if (m15 == 0) {
      int o = (og0 + g) * 16 + quad * 4;
#pragma unroll
      for (int r = 0; r < 4; r++) {
        atomicAdd(&ssum[o + r], rs[r]);
        atomicAdd(&ssq[o + r], rq[r]);
      }
    }
  }
}

template <int NG, int NTG>
__device__ inline void store_and_stats_h(f32x4 (&dacc)[NG][NTG],
                                         _Float16* __restrict__ outb,
                                         float* __restrict__ ssum,
                                         float* __restrict__ ssq, int tbase,
                                         int og0, int quad, int m15) {
#pragma unroll
  for (int g = 0; g < NG; g++) {
    float rs[4] = {0.f, 0.f, 0.f, 0.f}, rq[4] = {0.f, 0.f, 0.f, 0.f};
#pragma unroll
    for (int tg = 0; tg < NTG; tg++) {
      int t = tbase + tg * 16 + m15;
      bool valid = t < T;
      f32x4 d = dacc[g][tg];
      if (valid) {
        half4 h;
#pragma unroll
        for (int r = 0; r < 4; r++) h[r] = (_Float16)d[r];
        *(half4*)(outb + (size_t)t * C + (og0 + g) * 16 + quad * 4) = h;
      }
#pragma unroll
      for (int r = 0; r < 4; r++) {
        float v = valid ? d[r] : 0.f;
        rs[r] += v;
        rq[r] += v * v;
      }
    }
#pragma unroll
    for (int sh = 1; sh < 16; sh <<= 1) {
#pragma unroll
      for (int r = 0; r < 4; r++) {
        rs[r] += __shfl_xor(rs[r], sh);
        rq[r] += __shfl_xor(rq[r], sh);
      }
    }
    if (m15 == 0) {
      int o = (og0 + g) * 16 + quad * 4;
#pragma unroll
      for (int r = 0; r < 4; r++) {
        atomicAdd(&ssum[o + r], rs[r]);
        atomicAdd(&ssq[o + r], rq[r]);
      }
    }
  }
}

// ---------------------------------------------------------------------------
// Fused conv1 (KW=9, PAD=4) + conv3 (KW=1), R4 structure + one change:
// DOUBLE-BUFFERED PER-SLICE A-REGISTER PREFETCH. One slice = one kw's
// 8 A-frags (4 ic x 2 og) = 32 VGPR. Slice sl+1's loads are issued before
// slice sl's 16 MFMAs, so the L2 latency (~300cy) hides under a full
// slice of compute (load->use distance ~300+cy wall at 4 waves/SIMD).
// Slice 0 (= conv3's w3) is issued BEFORE input staging. launch_bounds
// (512,4): VGPR cap 128, 16 waves/CU. Geometry unchanged from R4:
// 8 waves, og0=(wv&3)*2, t-half=(wv>>2)*32, NG=2 x NTG=2.
// ---------------------------------------------------------------------------
__global__ __launch_bounds__(512, 4) void conv13(
    const _Float16* __restrict__ in, const _Float16* __restrict__ w9,
    const _Float16* __restrict__ w1, _Float16* __restrict__ out1,
    _Float16* __restrict__ out3, float* __restrict__ gS1,
    float* __restrict__ gQ1, float* __restrict__ gS3,
    float* __restrict__ gQ3) {
  constexpr int PAD = 4;
  constexpr int ROWS = NT + 8;  // 72
  __shared__ __align__(16) _Float16 sh[ROWS * WPAD];
  __shared__ float ssum1[C], ssq1[C], ssum3[C], ssq3[C];

  const int tid = threadIdx.x;
  const int tile = blockIdx.x;
  const int b = blockIdx.y;
  const int t0 = tile * NT;

  const int wv = tid >> 6;
  const int lane = tid & 63;
  const int quad = lane >> 4;
  const int m15 = lane & 15;
  const int og0 = (wv & 3) * 2;
  const int tr0 = (wv >> 2) * 32;

  const half8* __restrict__ A9 = (const half8*)w9;
  const half8* __restrict__ A1 = (const half8*)w1;

  // Slice sl: 0 = conv3 (w3), 1..9 = conv1 kw = sl-1. One kw-slice of A
  // in half8 units has stride 16*C.
  auto loadA = [&](half8 (&a)[8], int sl) {
    const half8* __restrict__ Asrc =
        (sl == 0) ? A1 : (A9 + (size_t)(sl - 1) * (16 * C));
#pragma unroll
    for (int ic = 0; ic < 4; ic++)
#pragma unroll
      for (int g = 0; g < 2; g++)
        a[ic * 2 + g] = Asrc[(ic * 4 + quad) * C + (og0 + g) * 16 + m15];
  };

  auto compute = [&](half8 (&a)[8], f32x4 (&D)[2][2], int rofs) {
#pragma unroll
    for (int ic = 0; ic < 4; ic++) {
      const int kof = ic * 32 + quad * 8;
      half8 bf[2];
#pragma unroll
      for (int tg = 0; tg < 2; tg++)
        bf[tg] = *(const half8*)(sh + (tr0 + tg * 16 + m15 + rofs) * WPAD + kof);
#pragma unroll
      for (int g = 0; g < 2; g++)
#pragma unroll
        for (int tg = 0; tg < 2; tg++)
          D[g][tg] = __builtin_amdgcn_mfma_f32_16x16x32_f16(
              a[ic * 2 + g], bf[tg], D[g][tg], 0, 0, 0);
    }
  };

  half8 apA[8], apB[8];
  loadA(apA, 0);  // issue slice 0 (w3) before staging — hides under the copy

  if (tid < 128) {
    ssum1[tid] = 0.f; ssq1[tid] = 0.f;
    ssum3[tid] = 0.f; ssq3[tid] = 0.f;
  }

  // Stage fp16 rows [t0-PAD, t0-PAD+ROWS) — pure copy, 16B loads.
  const _Float16* __restrict__ inb = in + (size_t)b * T * C;
  for (int e = tid; e < ROWS * 16; e += 512) {
    int r = e >> 4;
    int c8 = e & 15;
    int t = t0 - PAD + r;
    half8 v = h8zero();
    if (t >= 0 && t < T) v = *(const half8*)(inb + (size_t)t * C + c8 * 8);
    *(half8*)&sh[r * WPAD + c8 * 8] = v;
  }
  __syncthreads();

  // --- slice 0: conv3 (retire d3 before conv1's accumulator goes live) ---
  loadA(apB, 1);
  {
    f32x4 d3[2][2];
#pragma unroll
    for (int g = 0; g < 2; g++)
#pragma unroll
      for (int tg = 0; tg < 2; tg++) d3[g][tg] = f32x4{0.f, 0.f, 0.f, 0.f};
    compute(apA, d3, PAD);
    _Float16* __restrict__ o3b = out3 + (size_t)b * T * C;
    store_and_stats_h<2, 2>(d3, o3b, ssum3, ssq3, t0 + tr0, og0, quad, m15);
  }

  // --- slices 1..9: conv1, ping-pong prefetch one slice ahead ---
  f32x4 d1[2][2];
#pragma unroll
  for (int g = 0; g < 2; g++)
#pragma unroll
    for (int tg = 0; tg < 2; tg++) d1[g][tg] = f32x4{0.f, 0.f, 0.f, 0.f};

#pragma unroll
  for (int sl = 1; sl < 10; ++sl) {
    half8(&cur)[8] = (sl & 1) ? apB : apA;
    half8(&nxt)[8] = (sl & 1) ? apA : apB;
    if (sl + 1 < 10) loadA(nxt, sl + 1);
    compute(cur, d1, sl - 1);
  }

  _Float16* __restrict__ o1b = out1 + (size_t)b * T * C;
  store_and_stats_h<2, 2>(d1, o1b, ssum1, ssq1, t0 + tr0, og0, quad, m15);
  __syncthreads();
  if (tid < 128) {
    atomicAdd(&gS1[tid], ssum1[tid]);
    atomicAdd(&gQ1[tid], ssq1[tid]);
    atomicAdd(&gS3[tid], ssum3[tid]);
    atomicAdd(&gQ3[tid], ssq3[tid]);
  }
}

// ---------------------------------------------------------------------------
// conv2 (KW=9, PAD=4): BN+relu on staging from inline stats; same
// per-slice A-register double-buffer prefetch.
// ---------------------------------------------------------------------------
__global__ __launch_bounds__(512, 4) void conv2_bn(
    const _Float16* __restrict__ in, const _Float16* __restrict__ wf,
    const float* __restrict__ bnS, const float* __restrict__ bnQ,
    _Float16* __restrict__ out, float* __restrict__ gS,
    float* __restrict__ gQ) {
  constexpr int KW = 9, PAD = 4;
  constexpr int ROWS = NT + KW - 1;  // 72
  __shared__ __align__(16) _Float16 sh[ROWS * WPAD];
  __shared__ float ssum[C], ssq[C];
  __shared__ float sbm[C], sbr[C];

  const int tid = threadIdx.x;
  const int tile = blockIdx.x;
  const int b = blockIdx.y;
  const int t0 = tile * NT;

  const int wv = tid >> 6;
  const int lane = tid & 63;
  const int quad = lane >> 4;
  const int m15 = lane & 15;
  const int og0 = (wv & 3) * 2;
  const int tr0 = (wv >> 2) * 32;

  const half8* __restrict__ Af = (const half8*)wf;

  auto loadA = [&](half8 (&a)[8], int sl) {
    const half8* __restrict__ Asrc = Af + (size_t)sl * (16 * C);
#pragma unroll
    for (int ic = 0; ic < 4; ic++)
#pragma unroll
      for (int g = 0; g < 2; g++)
        a[ic * 2 + g] = Asrc[(ic * 4 + quad) * C + (og0 + g) * 16 + m15];
  };

  half8 apA[8], apB[8];
  loadA(apA, 0);  // issue slice 0 before staging

  if (tid < 128) {
    const float invn = 1.f / 64000.f;
    float m = bnS[tid] * invn;
    sbm[tid] = m;
    sbr[tid] = rsqrtf(bnQ[tid] * invn - m * m + 1e-5f);
    ssum[tid] = 0.f;
    ssq[tid] = 0.f;
  }
  __syncthreads();  // BN params ready before staging uses them

  const _Float16* __restrict__ inb = in + (size_t)b * T * C;
  for (int e = tid; e < ROWS * 16; e += 512) {
    int r = e >> 4;
    int c8 = e & 15;
    int t = t0 - PAD + r;
    half8 v = h8zero();
    if (t >= 0 && t < T) {
      half8 u = *(const half8*)(inb + (size_t)t * C + c8 * 8);
      int c = c8 * 8;
#pragma unroll
      for (int j = 0; j < 8; j++) {
        float f = (float)u[j];
        f = fmaxf((f - sbm[c + j]) * sbr[c + j], 0.f);
        v[j] = (_Float16)f;
      }
    }
    *(half8*)&sh[r * WPAD + c8 * 8] = v;
  }
  __syncthreads();

  f32x4 dacc[2][2];
#pragma unroll
  for (int g = 0; g < 2; g++)
#pragma unroll
    for (int tg = 0; tg < 2; tg++) dacc[g][tg] = f32x4{0.f, 0.f, 0.f, 0.f};

#pragma unroll
  for (int sl = 0; sl < 9; ++sl) {
    half8(&cur)[8] = (sl & 1) ? apB : apA;
    half8(&nxt)[8] = (sl & 1) ? apA : apB;
    if (sl + 1 < 9) loadA(nxt, sl + 1);
#pragma unroll
    for (int ic = 0; ic < 4; ic++) {
      const int kof = ic * 32 + quad * 8;
      half8 bf[2];
#pragma unroll
      for (int tg = 0; tg < 2; tg++)
        bf[tg] = *(const half8*)(sh + (tr0 + tg * 16 + m15 + sl) * WPAD + kof);
#pragma unroll
      for (int g = 0; g < 2; g++)
#pragma unroll
        for (int tg = 0; tg < 2; tg++)
          dacc[g][tg] = __builtin_amdgcn_mfma_f32_16x16x32_f16(
              cur[ic * 2 + g], bf[tg], dacc[g][tg], 0, 0, 0);
    }
  }

  _Float16* __restrict__ outb = out + (size_t)b * T * C;
  store_and_stats_h<2, 2>(dacc, outb, ssum, ssq, t0 + tr0, og0, quad, m15);
  __syncthreads();
  if (tid < 128) {
    atomicAdd(&gS[tid], ssum[tid]);
    atomicAdd(&gQ[tid], ssq[tid]);
  }
}

// ---------------------------------------------------------------------------
// conv0: single fp16 16x16x32 MFMA. in x[B][80][T] (t fastest), K=96(pad) x 3.
// Output z fp32 (state). 256 threads, one dispatch — unchanged.
// ---------------------------------------------------------------------------
__global__ __launch_bounds__(256) void conv0_mfma(
    const float* __restrict__ in, const _Float16* __restrict__ wf,
    float* __restrict__ out, float* __restrict__ gS, float* __restrict__ gQ) {
  constexpr int KW = 3, PAD = 1;
  constexpr int ROWS = NT + KW - 1;  // 66
  __shared__ __align__(16) _Float16 sh[ROWS * IPAD0];
  __shared__ float ssum[C], ssq[C];

  const int tid = threadIdx.x;
  const int tile = blockIdx.x;
  const int b = blockIdx.y;
  const int t0 = tile * NT;

  if (tid < 128) { ssum[tid] = 0.f; ssq[tid] = 0.f; }
  __syncthreads();

  const float* __restrict__ inb = in + (size_t)b * CIN * T;
  for (int e = tid; e < I0 * ROWS; e += 256) {
    int i = e / ROWS;
    int r = e % ROWS;
    int t = t0 - PAD + r;
    float v = 0.f;
    if (i < CIN && t >= 0 && t < T) v = inb[(size_t)i * T + t];
    sh[r * IPAD0 + i] = (_Float16)v;
  }
  __syncthreads();

  const int wv = tid >> 6;
  const int lane = tid & 63;
  const int quad = lane >> 4;
  const int m15 = lane & 15;
  const int og0 = wv * 2;

  f32x4 dacc[2][4];
#pragma unroll
  for (int g = 0; g < 2; g++)
#pragma unroll
    for (int tg = 0; tg < 4; tg++) dacc[g][tg] = f32x4{0.f, 0.f, 0.f, 0.f};

  for (int kw = 0; kw < KW; kw++) {
    const _Float16* __restrict__ wk = wf + (size_t)kw * C * I0;
#pragma unroll
    for (int ic = 0; ic < 3; ic++) {
      const int kof = ic * 32 + quad * 8;
      half8 af[2];
#pragma unroll
      for (int g = 0; g < 2; g++) {
        size_t off = (size_t)((og0 + g) * 16 + m15) * I0 + kof;
        af[g] = *(const half8*)(wk + off);
      }
      half8 bf[4];
#pragma unroll
      for (int tg = 0; tg < 4; tg++) {
        int off = (tg * 16 + m15 + kw) * IPAD0 + kof;
        bf[tg] = *(const half8*)(sh + off);
      }
#pragma unroll
      for (int g = 0; g < 2; g++)
#pragma unroll
        for (int tg = 0; tg < 4; tg++)
          dacc[g][tg] = __builtin_amdgcn_mfma_f32_16x16x32_f16(
              af[g], bf[tg], dacc[g][tg], 0, 0, 0);
    }
  }

  float* __restrict__ outb = out + (size_t)b * T * C;
  store_and_stats_f<2, 4>(dacc, outb, ssum, ssq, t0, og0, quad, m15);
  __syncthreads();
  if (tid < 128) {
    atomicAdd(&gS[tid], ssum[tid]);
    atomicAdd(&gQ[tid], ssq[tid]);
  }
}

// ---------------------------------------------------------------------------
// z = relu((z - m[c]) * r[c]) in place (fp32) + fp16 snapshot for conv13.
// ---------------------------------------------------------------------------
__global__ __launch_bounds__(256) void apply_bn_relu(
    float* __restrict__ x, const float* __restrict__ S,
    const float* __restrict__ Q, _Float16* __restrict__ zh) {
  __shared__ float sm[C], sr[C];
  if (threadIdx.x < 128) {
    const float invn = 1.f / 64000.f;
    float m = S[threadIdx.x] * invn;
    sm[threadIdx.x] = m;
    sr[threadIdx.x] = rsqrtf(Q[threadIdx.x] * invn - m * m + 1e-5f);
  }
  __syncthreads();
  const size_t total4 = NBCT / 4;
  size_t stride = (size_t)gridDim.x * 256;
  for (size_t i4 = (size_t)blockIdx.x * 256 + threadIdx.x; i4 < total4;
       i4 += stride) {
    int c = (int)((i4 & 31) * 4);
    float4 v = ((float4*)x)[i4];
    v.x = fmaxf((v.x - sm[c]) * sr[c], 0.f);
    v.y = fmaxf((v.y - sm[c + 1]) * sr[c + 1], 0.f);
    v.z = fmaxf((v.z - sm[c + 2]) * sr[c + 2], 0.f);
    v.w = fmaxf((v.w - sm[c + 3]) * sr[c + 3], 0.f);
    ((float4*)x)[i4] = v;
    half4 h;
    h[0] = (_Float16)v.x;
    h[1] = (_Float16)v.y;
    h[2] = (_Float16)v.z;
    h[3] = (_Float16)v.w;
    *(half4*)(zh + i4 * 4) = h;
  }
}

// ---------------------------------------------------------------------------
// combine: k = relu(bn2(t2) + relu(bn3(t3))); RK4 update.
// t2/t3 fp16; z/acc fp32; zi16 (fp16 next-conv input) always written;
// z (fp32 state) written only on fin.
// ---------------------------------------------------------------------------
__global__ __launch_bounds__(256) void combine_kernel(
    const _Float16* __restrict__ t2, const _Float16* __restrict__ t3,
    const float* __restrict__ S2, const float* __restrict__ Q2,
    const float* __restrict__ S3, const float* __restrict__ Q3,
    float* __restrict__ z, float* __restrict__ acc,
    _Float16* __restrict__ zi16, float wacc, float anext, int init, int fin) {
  __shared__ float sm2[C], sr2[C], sm3[C], sr3[C];
  if (threadIdx.x < 128) {
    const float invn = 1.f / 64000.f;
    float m2v = S2[threadIdx.x] * invn;
    sm2[threadIdx.x] = m2v;
    sr2[threadIdx.x] = rsqrtf(Q2[threadIdx.x] * invn - m2v * m2v + 1e-5f);
    float m3v = S3[threadIdx.x] * invn;
    sm3[threadIdx.x] = m3v;
    sr3[threadIdx.x] = rsqrtf(Q3[threadIdx.x] * invn - m3v * m3v + 1e-5f);
  }
  __syncthreads();
  const size_t total4 = NBCT / 4;
  size_t stride = (size_t)gridDim.x * 256;
  for (size_t i4 = (size_t)blockIdx.x * 256 + threadIdx.x; i4 < total4;
       i4 += stride) {
    int c = (int)((i4 & 31) * 4);
    size_t off = i4 * 4;
    half4 h2 = *(const half4*)(t2 + off);
    half4 h3 = *(const half4*)(t3 + off);
    float4 vz = *(const float4*)(z + off);
    float k[4];
#pragma unroll
    for (int j = 0; j < 4; j++) {
      float f2 = (float)h2[j];
      float f3 = (float)h3[j];
      k[j] = fmaxf((f2 - sm2[c + j]) * sr2[c + j] +
                       fmaxf((f3 - sm3[c + j]) * sr3[c + j], 0.f),
                   0.f);
    }
    float va[4];
    if (init) {
#pragma unroll
      for (int j = 0; j < 4; j++) va[j] = wacc * k[j];
    } else {
      float4 a = *(const float4*)(acc + off);
      va[0] = a.x + wacc * k[0];
      va[1] = a.y + wacc * k[1];
      va[2] = a.z + wacc * k[2];
      va[3] = a.w + wacc * k[3];
    }
    float vzf[4] = {vz.x, vz.y, vz.z, vz.w};
    float vo[4];
    if (fin) {
#pragma unroll
      for (int j = 0; j < 4; j++) vo[j] = vzf[j] + anext * va[j];
      float4 w4 = make_float4(vo[0], vo[1], vo[2], vo[3]);
      *(float4*)(z + off) = w4;
    } else {
      float4 a4 = make_float4(va[0], va[1], va[2], va[3]);
      *(float4*)(acc + off) = a4;
#pragma unroll
      for (int j = 0; j < 4; j++) vo[j] = vzf[j] + anext * k[j];
    }
    half4 ho;
#pragma unroll
    for (int j = 0; j < 4; j++) ho[j] = (_Float16)vo[j];
    *(half4*)(zi16 + off) = ho;
  }
}

// ---------------------------------------------------------------------------
// head, phase 1: partial t-sums. grid (B, 4), each block sums 125 t's.
// ---------------------------------------------------------------------------
__global__ __launch_bounds__(256) void feat_part(
    const float* __restrict__ z, float* __restrict__ fp) {
  const int b = blockIdx.x;
  const int s = blockIdx.y;
  const int c = threadIdx.x & 127;
  const int h = threadIdx.x >> 7;
  const float* zb = z + (size_t)b * T * C;
  float sum = 0.f;
  for (int t = s * 125 + h; t < (s + 1) * 125; t += 2)
    sum += zb[(size_t)t * C + c];
  __shared__ float sf[2][C];
  sf[h][c] = sum;
  __syncthreads();
  if (threadIdx.x < 128)
    fp[((size_t)b * 4 + s) * C + threadIdx.x] =
        sf[0][threadIdx.x] + sf[1][threadIdx.x];
}

// head, phase 2: feat = sum(partials)/500; out = feat @ ow^T + ob.
__global__ __launch_bounds__(256) void head2(
    const float* __restrict__ fp, const float* __restrict__ ow,
    const float* __restrict__ ob, float* __restrict__ out) {
  const int b = blockIdx.x;
  __shared__ float feat[C];
  if (threadIdx.x < 128) {
    float s = 0.f;
#pragma unroll
    for (int p = 0; p < 4; p++) s += fp[((size_t)b * 4 + p) * C + threadIdx.x];
    feat[threadIdx.x] = s * (1.f / 500.f);
  }
  __syncthreads();
  if (threadIdx.x < NL) {
    int l = threadIdx.x;
    float o = ob[l];
    for (int j = 0; j < C; j++) o = fmaf(feat[j], ow[l * C + j], o);
    out[b * NL + l] = o;
  }
}

// ---------------------------------------------------------------------------
extern "C" void kernel_launch(void* const* d_in, const int* in_sizes, int n_in,
                              void* d_out, int out_size, void* d_ws,
                              size_t ws_size, hipStream_t stream) {
  const float* x  = (const float*)d_in[0];
  const float* w0 = (const float*)d_in[1];
  const float* w1 = (const float*)d_in[2];
  const float* w2 = (const float*)d_in[3];
  const float* w3 = (const float*)d_in[4];
  const float* ow = (const float*)d_in[5];
  const float* ob = (const float*)d_in[6];
  float* out = (float*)d_out;

  static float *z, *acc, *Sg, *Qg, *featp;
  static _Float16 *zi16, *t1, *t2, *t3;
  static _Float16 *w0f, *w1f, *w2f, *w3f;
  static bool inited = false;
  if (!inited) {
    void* p;
#define GET(sym, var) hipGetSymbolAddress(&p, HIP_SYMBOL(sym)); var = (decltype(var))p;
    GET(g_z, z) GET(g_acc, acc) GET(g_zi16, zi16)
    GET(g_t1, t1) GET(g_t2, t2) GET(g_t3, t3)
    GET(g_S, Sg) GET(g_Q, Qg) GET(g_featp, featp)
    GET(g_w0f, w0f) GET(g_w1f, w1f) GET(g_w2f, w2f) GET(g_w3f, w3f)
#undef GET
    inited = true;
  }

  // Zero stat slots + weight prep (cheap, every launch)
  zero_stats<<<(NSLOT * C + 255) / 256, 256, 0, stream>>>(Sg, Qg);
  prep_w0_f16<<<(3 * C * I0 + 255) / 256, 256, 0, stream>>>(w0, w0f);
  prep_weights_f16<9><<<(C * C * 9 + 255) / 256, 256, 0, stream>>>(w1, w1f);
  prep_weights_f16<9><<<(C * C * 9 + 255) / 256, 256, 0, stream>>>(w2, w2f);
  prep_weights_f16<1><<<(C * C * 1 + 255) / 256, 256, 0, stream>>>(w3, w3f);

  const dim3 convGrid(8, B);   // NT=64 tiles -> 1024 blocks of 512 thr
  const int ewGrid = 1024;
  const float dt = 0.25f;

  // conv0 -> bn -> relu (into z fp32 + zi16 fp16). Stats slot 48.
  float* S0 = Sg + 48 * C;
  float* Q0 = Qg + 48 * C;
  conv0_mfma<<<dim3(8, B), 256, 0, stream>>>(x, w0f, z, S0, Q0);
  apply_bn_relu<<<ewGrid, 256, 0, stream>>>(z, S0, Q0, zi16);

  const float waccs[4] = {1.f, 2.f, 2.f, 1.f};
  const float anexts[4] = {0.5f * dt, 0.5f * dt, dt, dt / 6.f};

  for (int step = 0; step < 4; step++) {
    for (int s = 0; s < 4; s++) {
      int base = ((step * 4 + s) * 3) * C;   // slots: t1, t3, t2
      float* S1 = Sg + base;       float* Q1 = Qg + base;
      float* S3 = Sg + base + C;   float* Q3 = Qg + base + C;
      float* S2 = Sg + base + 2*C; float* Q2 = Qg + base + 2*C;
      conv13<<<convGrid, 512, 0, stream>>>(
          zi16, w1f, w3f, t1, t3, S1, Q1, S3, Q3);
      conv2_bn<<<convGrid, 512, 0, stream>>>(
          t1, w2f, S1, Q1, t2, S2, Q2);
      combine_kernel<<<ewGrid, 256, 0, stream>>>(
          t2, t3, S2, Q2, S3, Q3, z, acc, zi16,
          waccs[s], anexts[s], (s == 0) ? 1 : 0, (s == 3) ? 1 : 0);
    }
  }

  feat_part<<<dim3(B, 4), 256, 0, stream>>>(z, featp);
  head2<<<B, 256, 0, stream>>>(featp, ow, ob, out);
}